// Round 1
// baseline (1467.191 us; speedup 1.0000x reference)
//
#include <hip/hip_runtime.h>
#include <hip/hip_bf16.h>

typedef __attribute__((ext_vector_type(8))) short bf16x8;
typedef __attribute__((ext_vector_type(4))) float f32x4;

__device__ __forceinline__ ushort f2bf(float f) {
  union { float f; unsigned u; } x; x.f = f;
  unsigned r = x.u + 0x7fffu + ((x.u >> 16) & 1u);
  return (ushort)(r >> 16);
}

// ---------------- f32 -> bf16 convert (grid-stride) ----------------
__global__ void cvt_kernel(const float* __restrict__ in, ushort* __restrict__ out, int n) {
  int i = blockIdx.x * blockDim.x + threadIdx.x;
  int stride = gridDim.x * blockDim.x;
  for (; i < n; i += stride) out[i] = f2bf(in[i]);
}

// ---------------- LayerNorm: 1 wave per row of 768, bf16 out ----------------
__global__ __launch_bounds__(64) void ln_kernel(
    const float* __restrict__ x, const float* __restrict__ w,
    const float* __restrict__ b, ushort* __restrict__ out) {
  int row = blockIdx.x;
  int lane = threadIdx.x;
  const float* xr = x + (size_t)row * 768;
  float4 v[3];
  float s = 0.f, sq = 0.f;
#pragma unroll
  for (int i = 0; i < 3; i++) {
    v[i] = *(const float4*)(xr + i * 256 + lane * 4);
    s += v[i].x + v[i].y + v[i].z + v[i].w;
    sq += v[i].x * v[i].x + v[i].y * v[i].y + v[i].z * v[i].z + v[i].w * v[i].w;
  }
#pragma unroll
  for (int m = 1; m < 64; m <<= 1) { s += __shfl_xor(s, m); sq += __shfl_xor(sq, m); }
  float mean = s * (1.f / 768.f);
  float var = sq * (1.f / 768.f) - mean * mean;
  float rstd = rsqrtf(var + 1e-5f);
  ushort* orow = out + (size_t)row * 768;
#pragma unroll
  for (int i = 0; i < 3; i++) {
    int d = i * 256 + lane * 4;
    float4 wv = *(const float4*)(w + d);
    float4 bv = *(const float4*)(b + d);
    ushort4 o;
    o.x = f2bf((v[i].x - mean) * rstd * wv.x + bv.x);
    o.y = f2bf((v[i].y - mean) * rstd * wv.y + bv.y);
    o.z = f2bf((v[i].z - mean) * rstd * wv.z + bv.z);
    o.w = f2bf((v[i].w - mean) * rstd * wv.w + bv.w);
    *(ushort4*)(orow + d) = o;
  }
}

// ---------------- GEMM: C[M,N] = A[M,K] * W[N,K]^T ----------------
// MODE 0: store bf16, no bias (QKV)
// MODE 1: store f32, +bias +res (proj / fc2 with residual)
// MODE 2: store bf16, +bias, exact GELU (fc1)
template <int MODE>
__global__ __launch_bounds__(256) void gemm_bt(
    const ushort* __restrict__ A, const ushort* __restrict__ W,
    const float* __restrict__ bias, const float* __restrict__ res,
    void* __restrict__ outp, int M, int N, int K) {
  int lane = threadIdx.x & 63;
  int wave = threadIdx.x >> 6;
  int l15 = lane & 15, lg = lane >> 4;
  int rowBlk = blockIdx.x * 64 + (wave & 1) * 32;
  int colBlk = blockIdx.y * 128 + (wave >> 1) * 64;
  const ushort* a0 = A + (size_t)(rowBlk + l15) * K + lg * 8;
  const ushort* a1 = a0 + (size_t)16 * K;
  const ushort* w0 = W + (size_t)(colBlk + l15) * K + lg * 8;
  f32x4 acc[2][4] = {};
  for (int k = 0; k < K; k += 32) {
    bf16x8 av0 = *(const bf16x8*)(a0 + k);
    bf16x8 av1 = *(const bf16x8*)(a1 + k);
#pragma unroll
    for (int c = 0; c < 4; c++) {
      bf16x8 wv = *(const bf16x8*)(w0 + (size_t)c * 16 * K + k);
      acc[0][c] = __builtin_amdgcn_mfma_f32_16x16x32_bf16(av0, wv, acc[0][c], 0, 0, 0);
      acc[1][c] = __builtin_amdgcn_mfma_f32_16x16x32_bf16(av1, wv, acc[1][c], 0, 0, 0);
    }
  }
#pragma unroll
  for (int rt = 0; rt < 2; rt++) {
#pragma unroll
    for (int c = 0; c < 4; c++) {
      int col = colBlk + c * 16 + l15;
      float bv = (MODE != 0) ? bias[col] : 0.f;
#pragma unroll
      for (int j = 0; j < 4; j++) {
        int row = rowBlk + rt * 16 + lg * 4 + j;
        if (row < M) {
          float vacc = acc[rt][c][j] + bv;
          size_t idx = (size_t)row * N + col;
          if (MODE == 1) {
            ((float*)outp)[idx] = vacc + res[idx];
          } else if (MODE == 2) {
            float g = 0.5f * vacc * (1.f + erff(vacc * 0.70710678118f));
            ((ushort*)outp)[idx] = f2bf(g);
          } else {
            ((ushort*)outp)[idx] = f2bf(vacc);
          }
        }
      }
    }
  }
}

// ---------------- Flash attention: 1 wave per (b, h, 32 q-rows) ----------------
// qkv rows: (b*N + n) x 2304, q at h*64, k at 768+h*64, v at 1536+h*64
__global__ __launch_bounds__(64) void attn_kernel(
    const ushort* __restrict__ qkv, ushort* __restrict__ o_out, int N) {
  __shared__ ushort pl[32 * 32];
  int lane = threadIdx.x;
  int l15 = lane & 15, lg = lane >> 4;
  int qb = blockIdx.x * 32;
  int b = blockIdx.y / 12, h = blockIdx.y % 12;
  const ushort* base = qkv + (size_t)b * N * 2304;
  const ushort* Qp = base + h * 64;
  const ushort* Kp = base + 768 + h * 64;
  const ushort* Vp = base + 1536 + h * 64;
  bf16x8 qf[2][2];
#pragma unroll
  for (int rt = 0; rt < 2; rt++)
#pragma unroll
    for (int kc = 0; kc < 2; kc++)
      qf[rt][kc] = *(const bf16x8*)(Qp + (size_t)(qb + rt * 16 + l15) * 2304 + kc * 32 + lg * 8);
  f32x4 oacc[2][4] = {};
  float mrun[2][4], lrun[2][4], corr[2][4];
#pragma unroll
  for (int rt = 0; rt < 2; rt++)
#pragma unroll
    for (int j = 0; j < 4; j++) { mrun[rt][j] = -1e30f; lrun[rt][j] = 0.f; }

  for (int k0 = 0; k0 < N; k0 += 32) {
    f32x4 s[2][2] = {};
#pragma unroll
    for (int kt = 0; kt < 2; kt++) {
#pragma unroll
      for (int kc = 0; kc < 2; kc++) {
        bf16x8 kf = *(const bf16x8*)(Kp + (size_t)(k0 + kt * 16 + l15) * 2304 + kc * 32 + lg * 8);
        s[0][kt] = __builtin_amdgcn_mfma_f32_16x16x32_bf16(qf[0][kc], kf, s[0][kt], 0, 0, 0);
        s[1][kt] = __builtin_amdgcn_mfma_f32_16x16x32_bf16(qf[1][kc], kf, s[1][kt], 0, 0, 0);
      }
    }
#pragma unroll
    for (int rt = 0; rt < 2; rt++) {
#pragma unroll
      for (int j = 0; j < 4; j++) {
        float s0 = s[rt][0][j] * 0.125f;
        float s1 = s[rt][1][j] * 0.125f;
        if (k0 + l15 >= N) s0 = -1e30f;
        if (k0 + 16 + l15 >= N) s1 = -1e30f;
        float mx = fmaxf(s0, s1);
#pragma unroll
        for (int m = 1; m < 16; m <<= 1) mx = fmaxf(mx, __shfl_xor(mx, m));
        float mnew = fmaxf(mrun[rt][j], mx);
        float c = __expf(mrun[rt][j] - mnew);
        float p0 = __expf(s0 - mnew);
        float p1 = __expf(s1 - mnew);
        float rs = p0 + p1;
#pragma unroll
        for (int m = 1; m < 16; m <<= 1) rs += __shfl_xor(rs, m);
        mrun[rt][j] = mnew;
        lrun[rt][j] = lrun[rt][j] * c + rs;
        corr[rt][j] = c;
        int r = rt * 16 + lg * 4 + j;
        pl[r * 32 + l15] = f2bf(p0);
        pl[r * 32 + 16 + l15] = f2bf(p1);
      }
    }
#pragma unroll
    for (int rt = 0; rt < 2; rt++)
#pragma unroll
      for (int dt = 0; dt < 4; dt++)
#pragma unroll
        for (int j = 0; j < 4; j++) oacc[rt][dt][j] *= corr[rt][j];
    __syncthreads();
    bf16x8 pa0 = *(const bf16x8*)(pl + l15 * 32 + lg * 8);
    bf16x8 pa1 = *(const bf16x8*)(pl + (16 + l15) * 32 + lg * 8);
#pragma unroll
    for (int dt = 0; dt < 4; dt++) {
      bf16x8 vfr;
#pragma unroll
      for (int j = 0; j < 8; j++)
        vfr[j] = (short)Vp[(size_t)(k0 + lg * 8 + j) * 2304 + dt * 16 + l15];
      oacc[0][dt] = __builtin_amdgcn_mfma_f32_16x16x32_bf16(pa0, vfr, oacc[0][dt], 0, 0, 0);
      oacc[1][dt] = __builtin_amdgcn_mfma_f32_16x16x32_bf16(pa1, vfr, oacc[1][dt], 0, 0, 0);
    }
    __syncthreads();
  }
#pragma unroll
  for (int rt = 0; rt < 2; rt++) {
#pragma unroll
    for (int j = 0; j < 4; j++) {
      int n = qb + rt * 16 + lg * 4 + j;
      if (n < N) {
        float inv = 1.f / lrun[rt][j];
        ushort* orow = o_out + (size_t)(b * N + n) * 768 + h * 64;
#pragma unroll
        for (int dt = 0; dt < 4; dt++)
          orow[dt * 16 + l15] = f2bf(oacc[rt][dt][j] * inv);
      }
    }
  }
}

// ---------------- host-side orchestration ----------------
static void run_stream(const float* x, int B, int N,
                       const float* ln1_w, const float* ln1_b, const float* proj_b,
                       const float* ln2_w, const float* ln2_b,
                       const float* fc1_b, const float* fc2_b,
                       const ushort* wq, const ushort* wp, const ushort* w1, const ushort* w2,
                       ushort* bufA, ushort* bufQKV, ushort* bufFF,
                       float* out, hipStream_t stream) {
  int M = B * N;
  int gm = (M + 63) / 64;
  ln_kernel<<<M, 64, 0, stream>>>(x, ln1_w, ln1_b, bufA);
  gemm_bt<0><<<dim3(gm, 2304 / 128), 256, 0, stream>>>(bufA, wq, nullptr, nullptr, bufQKV, M, 2304, 768);
  attn_kernel<<<dim3((N + 31) / 32, B * 12), 64, 0, stream>>>(bufQKV, bufA, N);
  gemm_bt<1><<<dim3(gm, 768 / 128), 256, 0, stream>>>(bufA, wp, proj_b, x, out, M, 768, 768);
  ln_kernel<<<M, 64, 0, stream>>>(out, ln2_w, ln2_b, bufA);
  gemm_bt<2><<<dim3(gm, 3072 / 128), 256, 0, stream>>>(bufA, w1, fc1_b, nullptr, bufFF, M, 3072, 768);
  gemm_bt<1><<<dim3(gm, 768 / 128), 256, 0, stream>>>(bufFF, w2, fc2_b, out, out, M, 768, 3072);
}

extern "C" void kernel_launch(void* const* d_in, const int* in_sizes, int n_in,
                              void* d_out, int out_size, void* d_ws, size_t ws_size,
                              hipStream_t stream) {
  const float* x1 = (const float*)d_in[0];
  const float* x2 = (const float*)d_in[1];
  const float* ln1_w = (const float*)d_in[2];
  const float* ln1_b = (const float*)d_in[3];
  const float* qkv_w = (const float*)d_in[4];
  const float* proj_w = (const float*)d_in[5];
  const float* proj_b = (const float*)d_in[6];
  const float* ln2_w = (const float*)d_in[7];
  const float* ln2_b = (const float*)d_in[8];
  const float* fc1_w = (const float*)d_in[9];
  const float* fc1_b = (const float*)d_in[10];
  const float* fc2_w = (const float*)d_in[11];
  const float* fc2_b = (const float*)d_in[12];
  float* out = (float*)d_out;

  const int MPAD = 11008;  // 8*1370=10960 rounded to 64
  char* ws = (char*)d_ws;
  ushort* wq = (ushort*)ws;            ws += (size_t)2304 * 768 * 2;
  ushort* wp = (ushort*)ws;            ws += (size_t)768 * 768 * 2;
  ushort* w1 = (ushort*)ws;            ws += (size_t)3072 * 768 * 2;
  ushort* w2 = (ushort*)ws;            ws += (size_t)768 * 3072 * 2;
  ushort* bufA = (ushort*)ws;          ws += (size_t)MPAD * 768 * 2;
  ushort* bufQKV = (ushort*)ws;        ws += (size_t)MPAD * 2304 * 2;
  ushort* bufFF = (ushort*)ws;         ws += (size_t)MPAD * 3072 * 2;

  cvt_kernel<<<2048, 256, 0, stream>>>(qkv_w, wq, 2304 * 768);
  cvt_kernel<<<2048, 256, 0, stream>>>(proj_w, wp, 768 * 768);
  cvt_kernel<<<2048, 256, 0, stream>>>(fc1_w, w1, 3072 * 768);
  cvt_kernel<<<2048, 256, 0, stream>>>(fc2_w, w2, 768 * 3072);

  run_stream(x1, 8, 1370, ln1_w, ln1_b, proj_b, ln2_w, ln2_b, fc1_b, fc2_b,
             wq, wp, w1, w2, bufA, bufQKV, bufFF, out, stream);
  run_stream(x2, 8, 257, ln1_w, ln1_b, proj_b, ln2_w, ln2_b, fc1_b, fc2_b,
             wq, wp, w1, w2, bufA, bufQKV, bufFF, out + (size_t)8 * 1370 * 768, stream);
}

// Round 2
// 762.469 us; speedup vs baseline: 1.9243x; 1.9243x over previous
//
#include <hip/hip_runtime.h>
#include <hip/hip_bf16.h>

typedef __attribute__((ext_vector_type(8))) short bf16x8;
typedef __attribute__((ext_vector_type(4))) float f32x4;

#define GL_LDS16(g, l)                                                        \
  __builtin_amdgcn_global_load_lds((const __attribute__((address_space(1))) void*)(g), \
                                   (__attribute__((address_space(3))) void*)(l), 16, 0, 0)

__device__ __forceinline__ ushort f2bf(float f) {
  union { float f; unsigned u; } x; x.f = f;
  unsigned r = x.u + 0x7fffu + ((x.u >> 16) & 1u);
  return (ushort)(r >> 16);
}

// ---------------- f32 -> bf16 convert (grid-stride) ----------------
__global__ void cvt_kernel(const float* __restrict__ in, ushort* __restrict__ out, int n) {
  int i = blockIdx.x * blockDim.x + threadIdx.x;
  int stride = gridDim.x * blockDim.x;
  for (; i < n; i += stride) out[i] = f2bf(in[i]);
}

// ---------------- LayerNorm: 1 wave per row of 768, bf16 out ----------------
__global__ __launch_bounds__(64) void ln_kernel(
    const float* __restrict__ x, const float* __restrict__ w,
    const float* __restrict__ b, ushort* __restrict__ out) {
  int row = blockIdx.x;
  int lane = threadIdx.x;
  const float* xr = x + (size_t)row * 768;
  float4 v[3];
  float s = 0.f, sq = 0.f;
#pragma unroll
  for (int i = 0; i < 3; i++) {
    v[i] = *(const float4*)(xr + i * 256 + lane * 4);
    s += v[i].x + v[i].y + v[i].z + v[i].w;
    sq += v[i].x * v[i].x + v[i].y * v[i].y + v[i].z * v[i].z + v[i].w * v[i].w;
  }
#pragma unroll
  for (int m = 1; m < 64; m <<= 1) { s += __shfl_xor(s, m); sq += __shfl_xor(sq, m); }
  float mean = s * (1.f / 768.f);
  float var = sq * (1.f / 768.f) - mean * mean;
  float rstd = rsqrtf(var + 1e-5f);
  ushort* orow = out + (size_t)row * 768;
#pragma unroll
  for (int i = 0; i < 3; i++) {
    int d = i * 256 + lane * 4;
    float4 wv = *(const float4*)(w + d);
    float4 bv = *(const float4*)(b + d);
    ushort4 o;
    o.x = f2bf((v[i].x - mean) * rstd * wv.x + bv.x);
    o.y = f2bf((v[i].y - mean) * rstd * wv.y + bv.y);
    o.z = f2bf((v[i].z - mean) * rstd * wv.z + bv.z);
    o.w = f2bf((v[i].w - mean) * rstd * wv.w + bv.w);
    *(ushort4*)(orow + d) = o;
  }
}

// ---------------- Tiled GEMM: C[M,N] = A[M,K] * W[N,K]^T ----------------
// 128x128 tile, BK=64, 4 waves (2x2) each computing 64x64.
// LDS linear [128][64]; global source pre-swizzled chunk^(row&7); ds_read
// applies the same XOR (both-sides involution, rule #21).
// MODE 0: store bf16, no bias (QKV)
// MODE 1: store f32, +bias +res (proj / fc2 with residual)
// MODE 2: store bf16, +bias, exact GELU (fc1)
template <int MODE>
__global__ __launch_bounds__(256) void gemm_tile(
    const ushort* __restrict__ A, const ushort* __restrict__ W,
    const float* __restrict__ bias, const float* __restrict__ res,
    void* __restrict__ outp, int M, int N, int K) {
  __shared__ ushort lA[128 * 64];
  __shared__ ushort lB[128 * 64];
  const int t = threadIdx.x;
  const int lane = t & 63, wave = t >> 6;
  const int l15 = lane & 15, lg = lane >> 4;
  const int waveM = wave >> 1, waveN = wave & 1;
  const int rowBlk = blockIdx.x * 128;
  const int colBlk = blockIdx.y * 128;

  const int srow = (wave << 3) + (lane >> 3);  // 0..31 (row within 32-row group)
  const int schunk = lane & 7;                 // 16B chunk within 128B row

  f32x4 acc[4][4] = {};

  for (int k0 = 0; k0 < K; k0 += 64) {
    if (k0) __syncthreads();
#pragma unroll
    for (int i = 0; i < 4; i++) {
      int row = i * 32 + srow;
      int gchunk = schunk ^ (row & 7);
      GL_LDS16(A + (size_t)(rowBlk + row) * K + k0 + gchunk * 8,
               &lA[row * 64 + schunk * 8]);
      GL_LDS16(W + (size_t)(colBlk + row) * K + k0 + gchunk * 8,
               &lB[row * 64 + schunk * 8]);
    }
    __syncthreads();
#pragma unroll
    for (int kk = 0; kk < 2; kk++) {
      bf16x8 af[4], bfr[4];
#pragma unroll
      for (int m = 0; m < 4; m++) {
        int row = waveM * 64 + m * 16 + l15;
        af[m] = *(const bf16x8*)&lA[row * 64 + ((kk * 32 + lg * 8) ^ ((row & 7) << 3))];
      }
#pragma unroll
      for (int c = 0; c < 4; c++) {
        int row = waveN * 64 + c * 16 + l15;
        bfr[c] = *(const bf16x8*)&lB[row * 64 + ((kk * 32 + lg * 8) ^ ((row & 7) << 3))];
      }
#pragma unroll
      for (int m = 0; m < 4; m++)
#pragma unroll
        for (int c = 0; c < 4; c++)
          acc[m][c] = __builtin_amdgcn_mfma_f32_16x16x32_bf16(af[m], bfr[c], acc[m][c], 0, 0, 0);
    }
  }

#pragma unroll
  for (int m = 0; m < 4; m++) {
    int rowB = rowBlk + waveM * 64 + m * 16 + lg * 4;
#pragma unroll
    for (int c = 0; c < 4; c++) {
      int col = colBlk + waveN * 64 + c * 16 + l15;
      float bv = (MODE != 0) ? bias[col] : 0.f;
#pragma unroll
      for (int j = 0; j < 4; j++) {
        int r = rowB + j;
        if (r < M) {
          float v = acc[m][c][j] + bv;
          size_t idx = (size_t)r * N + col;
          if (MODE == 1) {
            ((float*)outp)[idx] = v + res[idx];
          } else if (MODE == 2) {
            float g = 0.5f * v * (1.f + erff(v * 0.70710678118f));
            ((ushort*)outp)[idx] = f2bf(g);
          } else {
            ((ushort*)outp)[idx] = f2bf(v);
          }
        }
      }
    }
  }
}

// ---------------- Flash attention: 1 wave per (b, h, 32 q-rows) ----------------
// qkv rows: (b*N + n) x 2304, q at h*64, k at 768+h*64, v at 1536+h*64
__global__ __launch_bounds__(64) void attn_kernel(
    const ushort* __restrict__ qkv, ushort* __restrict__ o_out, int N) {
  __shared__ ushort pl[32 * 32];
  int lane = threadIdx.x;
  int l15 = lane & 15, lg = lane >> 4;
  int qb = blockIdx.x * 32;
  int b = blockIdx.y / 12, h = blockIdx.y % 12;
  const ushort* base = qkv + (size_t)b * N * 2304;
  const ushort* Qp = base + h * 64;
  const ushort* Kp = base + 768 + h * 64;
  const ushort* Vp = base + 1536 + h * 64;
  bf16x8 qf[2][2];
#pragma unroll
  for (int rt = 0; rt < 2; rt++)
#pragma unroll
    for (int kc = 0; kc < 2; kc++)
      qf[rt][kc] = *(const bf16x8*)(Qp + (size_t)(qb + rt * 16 + l15) * 2304 + kc * 32 + lg * 8);
  f32x4 oacc[2][4] = {};
  float mrun[2][4], lrun[2][4], corr[2][4];
#pragma unroll
  for (int rt = 0; rt < 2; rt++)
#pragma unroll
    for (int j = 0; j < 4; j++) { mrun[rt][j] = -1e30f; lrun[rt][j] = 0.f; }

  for (int k0 = 0; k0 < N; k0 += 32) {
    f32x4 s[2][2] = {};
#pragma unroll
    for (int kt = 0; kt < 2; kt++) {
#pragma unroll
      for (int kc = 0; kc < 2; kc++) {
        bf16x8 kf = *(const bf16x8*)(Kp + (size_t)(k0 + kt * 16 + l15) * 2304 + kc * 32 + lg * 8);
        s[0][kt] = __builtin_amdgcn_mfma_f32_16x16x32_bf16(qf[0][kc], kf, s[0][kt], 0, 0, 0);
        s[1][kt] = __builtin_amdgcn_mfma_f32_16x16x32_bf16(qf[1][kc], kf, s[1][kt], 0, 0, 0);
      }
    }
#pragma unroll
    for (int rt = 0; rt < 2; rt++) {
#pragma unroll
      for (int j = 0; j < 4; j++) {
        float s0 = s[rt][0][j] * 0.125f;
        float s1 = s[rt][1][j] * 0.125f;
        if (k0 + l15 >= N) s0 = -1e30f;
        if (k0 + 16 + l15 >= N) s1 = -1e30f;
        float mx = fmaxf(s0, s1);
#pragma unroll
        for (int m = 1; m < 16; m <<= 1) mx = fmaxf(mx, __shfl_xor(mx, m));
        float mnew = fmaxf(mrun[rt][j], mx);
        float c = __expf(mrun[rt][j] - mnew);
        float p0 = __expf(s0 - mnew);
        float p1 = __expf(s1 - mnew);
        float rs = p0 + p1;
#pragma unroll
        for (int m = 1; m < 16; m <<= 1) rs += __shfl_xor(rs, m);
        mrun[rt][j] = mnew;
        lrun[rt][j] = lrun[rt][j] * c + rs;
        corr[rt][j] = c;
        int r = rt * 16 + lg * 4 + j;
        pl[r * 32 + l15] = f2bf(p0);
        pl[r * 32 + 16 + l15] = f2bf(p1);
      }
    }
#pragma unroll
    for (int rt = 0; rt < 2; rt++)
#pragma unroll
      for (int dt = 0; dt < 4; dt++)
#pragma unroll
        for (int j = 0; j < 4; j++) oacc[rt][dt][j] *= corr[rt][j];
    __syncthreads();
    bf16x8 pa0 = *(const bf16x8*)(pl + l15 * 32 + lg * 8);
    bf16x8 pa1 = *(const bf16x8*)(pl + (16 + l15) * 32 + lg * 8);
#pragma unroll
    for (int dt = 0; dt < 4; dt++) {
      bf16x8 vfr;
#pragma unroll
      for (int j = 0; j < 8; j++)
        vfr[j] = (short)Vp[(size_t)(k0 + lg * 8 + j) * 2304 + dt * 16 + l15];
      oacc[0][dt] = __builtin_amdgcn_mfma_f32_16x16x32_bf16(pa0, vfr, oacc[0][dt], 0, 0, 0);
      oacc[1][dt] = __builtin_amdgcn_mfma_f32_16x16x32_bf16(pa1, vfr, oacc[1][dt], 0, 0, 0);
    }
    __syncthreads();
  }
#pragma unroll
  for (int rt = 0; rt < 2; rt++) {
#pragma unroll
    for (int j = 0; j < 4; j++) {
      int n = qb + rt * 16 + lg * 4 + j;
      if (n < N) {
        float inv = 1.f / lrun[rt][j];
        ushort* orow = o_out + (size_t)(b * N + n) * 768 + h * 64;
#pragma unroll
        for (int dt = 0; dt < 4; dt++)
          orow[dt * 16 + l15] = f2bf(oacc[rt][dt][j] * inv);
      }
    }
  }
}

// ---------------- host-side orchestration ----------------
static void run_stream(const float* x, int B, int N,
                       const float* ln1_w, const float* ln1_b, const float* proj_b,
                       const float* ln2_w, const float* ln2_b,
                       const float* fc1_b, const float* fc2_b,
                       const ushort* wq, const ushort* wp, const ushort* w1, const ushort* w2,
                       ushort* bufA, ushort* bufQKV, ushort* bufFF,
                       float* out, hipStream_t stream) {
  int M = B * N;
  int gm = (M + 127) / 128;
  ln_kernel<<<M, 64, 0, stream>>>(x, ln1_w, ln1_b, bufA);
  gemm_tile<0><<<dim3(gm, 2304 / 128), 256, 0, stream>>>(bufA, wq, nullptr, nullptr, bufQKV, M, 2304, 768);
  attn_kernel<<<dim3((N + 31) / 32, B * 12), 64, 0, stream>>>(bufQKV, bufA, N);
  gemm_tile<1><<<dim3(gm, 768 / 128), 256, 0, stream>>>(bufA, wp, proj_b, x, out, M, 768, 768);
  ln_kernel<<<M, 64, 0, stream>>>(out, ln2_w, ln2_b, bufA);
  gemm_tile<2><<<dim3(gm, 3072 / 128), 256, 0, stream>>>(bufA, w1, fc1_b, nullptr, bufFF, M, 3072, 768);
  gemm_tile<1><<<dim3(gm, 768 / 128), 256, 0, stream>>>(bufFF, w2, fc2_b, out, out, M, 768, 3072);
}

extern "C" void kernel_launch(void* const* d_in, const int* in_sizes, int n_in,
                              void* d_out, int out_size, void* d_ws, size_t ws_size,
                              hipStream_t stream) {
  const float* x1 = (const float*)d_in[0];
  const float* x2 = (const float*)d_in[1];
  const float* ln1_w = (const float*)d_in[2];
  const float* ln1_b = (const float*)d_in[3];
  const float* qkv_w = (const float*)d_in[4];
  const float* proj_w = (const float*)d_in[5];
  const float* proj_b = (const float*)d_in[6];
  const float* ln2_w = (const float*)d_in[7];
  const float* ln2_b = (const float*)d_in[8];
  const float* fc1_w = (const float*)d_in[9];
  const float* fc1_b = (const float*)d_in[10];
  const float* fc2_w = (const float*)d_in[11];
  const float* fc2_b = (const float*)d_in[12];
  float* out = (float*)d_out;

  const int MPAD = 11008;  // 8*1370=10960 rounded to 86*128
  char* ws = (char*)d_ws;
  ushort* wq = (ushort*)ws;            ws += (size_t)2304 * 768 * 2;
  ushort* wp = (ushort*)ws;            ws += (size_t)768 * 768 * 2;
  ushort* w1 = (ushort*)ws;            ws += (size_t)3072 * 768 * 2;
  ushort* w2 = (ushort*)ws;            ws += (size_t)768 * 3072 * 2;
  ushort* bufA = (ushort*)ws;          ws += (size_t)MPAD * 768 * 2;
  ushort* bufQKV = (ushort*)ws;        ws += (size_t)MPAD * 2304 * 2;
  ushort* bufFF = (ushort*)ws;         ws += (size_t)MPAD * 3072 * 2;

  cvt_kernel<<<2048, 256, 0, stream>>>(qkv_w, wq, 2304 * 768);
  cvt_kernel<<<2048, 256, 0, stream>>>(proj_w, wp, 768 * 768);
  cvt_kernel<<<2048, 256, 0, stream>>>(fc1_w, w1, 3072 * 768);
  cvt_kernel<<<2048, 256, 0, stream>>>(fc2_w, w2, 768 * 3072);

  run_stream(x1, 8, 1370, ln1_w, ln1_b, proj_b, ln2_w, ln2_b, fc1_b, fc2_b,
             wq, wp, w1, w2, bufA, bufQKV, bufFF, out, stream);
  run_stream(x2, 8, 257, ln1_w, ln1_b, proj_b, ln2_w, ln2_b, fc1_b, fc2_b,
             wq, wp, w1, w2, bufA, bufQKV, bufFF, out + (size_t)8 * 1370 * 768, stream);
}

// Round 3
// 656.956 us; speedup vs baseline: 2.2333x; 1.1606x over previous
//
#include <hip/hip_runtime.h>
#include <hip/hip_bf16.h>

typedef __attribute__((ext_vector_type(8))) short bf16x8;
typedef __attribute__((ext_vector_type(4))) float f32x4;
typedef __attribute__((ext_vector_type(16))) float f32x16;

#define GL_LDS16(g, l)                                                        \
  __builtin_amdgcn_global_load_lds((const __attribute__((address_space(1))) void*)(g), \
                                   (__attribute__((address_space(3))) void*)(l), 16, 0, 0)

__device__ __forceinline__ ushort f2bf(float f) {
  union { float f; unsigned u; } x; x.f = f;
  unsigned r = x.u + 0x7fffu + ((x.u >> 16) & 1u);
  return (ushort)(r >> 16);
}

// ---------------- f32 -> bf16 convert (grid-stride) ----------------
__global__ void cvt_kernel(const float* __restrict__ in, ushort* __restrict__ out, int n) {
  int i = blockIdx.x * blockDim.x + threadIdx.x;
  int stride = gridDim.x * blockDim.x;
  for (; i < n; i += stride) out[i] = f2bf(in[i]);
}

// ---------------- LayerNorm: 1 wave per row of 768, bf16 out ----------------
__global__ __launch_bounds__(64) void ln_kernel(
    const float* __restrict__ x, const float* __restrict__ w,
    const float* __restrict__ b, ushort* __restrict__ out) {
  int row = blockIdx.x;
  int lane = threadIdx.x;
  const float* xr = x + (size_t)row * 768;
  float4 v[3];
  float s = 0.f, sq = 0.f;
#pragma unroll
  for (int i = 0; i < 3; i++) {
    v[i] = *(const float4*)(xr + i * 256 + lane * 4);
    s += v[i].x + v[i].y + v[i].z + v[i].w;
    sq += v[i].x * v[i].x + v[i].y * v[i].y + v[i].z * v[i].z + v[i].w * v[i].w;
  }
#pragma unroll
  for (int m = 1; m < 64; m <<= 1) { s += __shfl_xor(s, m); sq += __shfl_xor(sq, m); }
  float mean = s * (1.f / 768.f);
  float var = sq * (1.f / 768.f) - mean * mean;
  float rstd = rsqrtf(var + 1e-5f);
  ushort* orow = out + (size_t)row * 768;
#pragma unroll
  for (int i = 0; i < 3; i++) {
    int d = i * 256 + lane * 4;
    float4 wv = *(const float4*)(w + d);
    float4 bv = *(const float4*)(b + d);
    ushort4 o;
    o.x = f2bf((v[i].x - mean) * rstd * wv.x + bv.x);
    o.y = f2bf((v[i].y - mean) * rstd * wv.y + bv.y);
    o.z = f2bf((v[i].z - mean) * rstd * wv.z + bv.z);
    o.w = f2bf((v[i].w - mean) * rstd * wv.w + bv.w);
    *(ushort4*)(orow + d) = o;
  }
}

// ---------------- Tiled GEMM: C[M,N] = A[M,K] * W[N,K]^T ----------------
template <int MODE>
__global__ __launch_bounds__(256) void gemm_tile(
    const ushort* __restrict__ A, const ushort* __restrict__ W,
    const float* __restrict__ bias, const float* __restrict__ res,
    void* __restrict__ outp, int M, int N, int K) {
  __shared__ ushort lA[128 * 64];
  __shared__ ushort lB[128 * 64];
  const int t = threadIdx.x;
  const int lane = t & 63, wave = t >> 6;
  const int l15 = lane & 15, lg = lane >> 4;
  const int waveM = wave >> 1, waveN = wave & 1;
  const int rowBlk = blockIdx.x * 128;
  const int colBlk = blockIdx.y * 128;

  const int srow = (wave << 3) + (lane >> 3);
  const int schunk = lane & 7;

  f32x4 acc[4][4] = {};

  for (int k0 = 0; k0 < K; k0 += 64) {
    if (k0) __syncthreads();
#pragma unroll
    for (int i = 0; i < 4; i++) {
      int row = i * 32 + srow;
      int gchunk = schunk ^ (row & 7);
      GL_LDS16(A + (size_t)(rowBlk + row) * K + k0 + gchunk * 8,
               &lA[row * 64 + schunk * 8]);
      GL_LDS16(W + (size_t)(colBlk + row) * K + k0 + gchunk * 8,
               &lB[row * 64 + schunk * 8]);
    }
    __syncthreads();
#pragma unroll
    for (int kk = 0; kk < 2; kk++) {
      bf16x8 af[4], bfr[4];
#pragma unroll
      for (int m = 0; m < 4; m++) {
        int row = waveM * 64 + m * 16 + l15;
        af[m] = *(const bf16x8*)&lA[row * 64 + ((kk * 32 + lg * 8) ^ ((row & 7) << 3))];
      }
#pragma unroll
      for (int c = 0; c < 4; c++) {
        int row = waveN * 64 + c * 16 + l15;
        bfr[c] = *(const bf16x8*)&lB[row * 64 + ((kk * 32 + lg * 8) ^ ((row & 7) << 3))];
      }
#pragma unroll
      for (int m = 0; m < 4; m++)
#pragma unroll
        for (int c = 0; c < 4; c++)
          acc[m][c] = __builtin_amdgcn_mfma_f32_16x16x32_bf16(af[m], bfr[c], acc[m][c], 0, 0, 0);
    }
  }

#pragma unroll
  for (int m = 0; m < 4; m++) {
    int rowB = rowBlk + waveM * 64 + m * 16 + lg * 4;
#pragma unroll
    for (int c = 0; c < 4; c++) {
      int col = colBlk + waveN * 64 + c * 16 + l15;
      float bv = (MODE != 0) ? bias[col] : 0.f;
#pragma unroll
      for (int j = 0; j < 4; j++) {
        int r = rowB + j;
        if (r < M) {
          float v = acc[m][c][j] + bv;
          size_t idx = (size_t)r * N + col;
          if (MODE == 1) {
            ((float*)outp)[idx] = v + res[idx];
          } else if (MODE == 2) {
            float g = 0.5f * v * (1.f + erff(v * 0.70710678118f));
            ((ushort*)outp)[idx] = f2bf(g);
          } else {
            ((ushort*)outp)[idx] = f2bf(v);
          }
        }
      }
    }
  }
}

// ---------------- V transpose: qkv V part -> vt[bh][d][Npad] ----------------
__global__ __launch_bounds__(256) void vt_kernel(
    const ushort* __restrict__ qkv, ushort* __restrict__ vt, int N, int Npad) {
  __shared__ ushort lT[64 * 68];
  const int t = threadIdx.x;
  const int n0 = blockIdx.x * 64;
  const int bh = blockIdx.y;
  const int b = bh / 12, h = bh % 12;
  const ushort* Vp = qkv + (size_t)b * N * 2304 + 1536 + h * 64;
#pragma unroll
  for (int p = 0; p < 2; p++) {
    int nl = p * 32 + (t >> 3);
    int dc = t & 7;
    ushort4 v0 = {0, 0, 0, 0}, v1 = {0, 0, 0, 0};
    if (n0 + nl < N) {
      const ushort* src = Vp + (size_t)(n0 + nl) * 2304 + dc * 8;
      v0 = *(const ushort4*)src;
      v1 = *(const ushort4*)(src + 4);
    }
    *(ushort4*)&lT[nl * 68 + dc * 8] = v0;
    *(ushort4*)&lT[nl * 68 + dc * 8 + 4] = v1;
  }
  __syncthreads();
#pragma unroll
  for (int p = 0; p < 2; p++) {
    int d = p * 32 + (t >> 3);
    int nc = t & 7;
    ushort o[8];
#pragma unroll
    for (int j = 0; j < 8; j++) o[j] = lT[(nc * 8 + j) * 68 + d];
    ushort* dst = vt + (size_t)(bh * 64 + d) * Npad + n0 + nc * 8;
    *(ushort4*)dst = *(ushort4*)o;
    *(ushort4*)(dst + 4) = *(ushort4*)(o + 4);
  }
}

// ---------------- Flash attention: 4 waves/block, 32 q-rows/wave ----------------
// Swapped QK^T (mfma(K,Q)) with 32x32x16; P redistributed in-register.
// LDS tiles chunk-major: element (row,c) at slot (c>>3)*64+row (16B slots).
__global__ __launch_bounds__(256) void attn_kernel(
    const ushort* __restrict__ qkv, const ushort* __restrict__ vt,
    ushort* __restrict__ o_out, int N, int Npad) {
  __shared__ ushort lK[4096];
  __shared__ ushort lV[4096];
  const int t = threadIdx.x;
  const int lane = t & 63, wave = t >> 6;
  const int l31 = lane & 31, hi = lane >> 5;
  const int qb = blockIdx.x * 128;
  const int bh = blockIdx.y;
  const int b = bh / 12, h = bh % 12;
  const ushort* Qp = qkv + (size_t)b * N * 2304 + h * 64;
  const ushort* Kp = Qp + 768;
  const ushort* Vtp = vt + (size_t)bh * 64 * Npad;

  const int qrow = qb + wave * 32 + l31;
  bf16x8 qf[4];
#pragma unroll
  for (int kc = 0; kc < 4; kc++)
    qf[kc] = *(const bf16x8*)(Qp + (size_t)qrow * 2304 + kc * 16 + hi * 8);

  f32x16 oacc[2] = {};
  float mrun = -1e30f, lrun = 0.f;
  const float SC = 0.18033688011112042f;  // 0.125 * log2(e)

  const int nkv = (N + 63) / 64;
  for (int kv = 0; kv < nkv; kv++) {
    const int k0 = kv * 64;
    if (kv) __syncthreads();
#pragma unroll
    for (int p = 0; p < 2; p++) {
      int slot = p * 256 + t;
      int chunk = slot >> 6, row = slot & 63;
      GL_LDS16(Kp + (size_t)(k0 + row) * 2304 + chunk * 8, &lK[slot * 8]);
      GL_LDS16(Vtp + (size_t)row * Npad + k0 + chunk * 8, &lV[slot * 8]);
    }
    __syncthreads();
    const bool fullTile = (k0 + 64 <= N);
#pragma unroll
    for (int kt = 0; kt < 2; kt++) {
      f32x16 sacc = {};
#pragma unroll
      for (int kc = 0; kc < 4; kc++) {
        bf16x8 kf = *(const bf16x8*)&lK[(((kc * 2 + hi) << 6) + kt * 32 + l31) * 8];
        sacc = __builtin_amdgcn_mfma_f32_32x32x16_bf16(kf, qf[kc], sacc, 0, 0, 0);
      }
      float z[16];
      float mx = -1e30f;
#pragma unroll
      for (int r = 0; r < 16; r++) {
        z[r] = sacc[r] * SC;
        if (!fullTile) {
          int kg = k0 + kt * 32 + (r & 3) + ((r >> 2) << 3) + (hi << 2);
          if (kg >= N) z[r] = -1e30f;
        }
        mx = fmaxf(mx, z[r]);
      }
      mx = fmaxf(mx, __shfl_xor(mx, 32));
      float mnew = fmaxf(mrun, mx);
      float corr = exp2f(mrun - mnew);
      float rs = 0.f;
#pragma unroll
      for (int r = 0; r < 16; r++) { z[r] = exp2f(z[r] - mnew); rs += z[r]; }
      rs += __shfl_xor(rs, 32);
      lrun = lrun * corr + rs;
      mrun = mnew;
      oacc[0] *= corr;
      oacc[1] *= corr;
      unsigned w0[4], w1[4];
#pragma unroll
      for (int rr = 0; rr < 4; rr++) {
        asm("v_cvt_pk_bf16_f32 %0, %1, %2" : "=v"(w0[rr]) : "v"(z[4 * rr]), "v"(z[4 * rr + 1]));
        asm("v_cvt_pk_bf16_f32 %0, %1, %2" : "=v"(w1[rr]) : "v"(z[4 * rr + 2]), "v"(z[4 * rr + 3]));
      }
#pragma unroll
      for (int kc2 = 0; kc2 < 2; kc2++) {
        unsigned a0 = w0[2 * kc2], b0 = w0[2 * kc2 + 1];
        unsigned a1 = w1[2 * kc2], b1 = w1[2 * kc2 + 1];
        unsigned a0x = __shfl_xor(a0, 32), b0x = __shfl_xor(b0, 32);
        unsigned a1x = __shfl_xor(a1, 32), b1x = __shfl_xor(b1, 32);
        union { unsigned u[4]; bf16x8 v; } pa;
        pa.u[0] = hi ? b0x : a0;   // c pair (0,1): k = 16kc2+8hi+{0,1}
        pa.u[1] = hi ? b1x : a1;   // c pair (2,3)
        pa.u[2] = hi ? b0 : a0x;   // c pair (4,5)
        pa.u[3] = hi ? b1 : a1x;   // c pair (6,7)
        int kcg = kt * 2 + kc2;
#pragma unroll
        for (int dt = 0; dt < 2; dt++) {
          bf16x8 vf = *(const bf16x8*)&lV[(((kcg * 2 + hi) << 6) + dt * 32 + l31) * 8];
          oacc[dt] = __builtin_amdgcn_mfma_f32_32x32x16_bf16(pa.v, vf, oacc[dt], 0, 0, 0);
        }
      }
    }
  }
  float inv = 1.f / lrun;
#pragma unroll
  for (int dt = 0; dt < 2; dt++)
#pragma unroll
    for (int r = 0; r < 16; r++) {
      int q = qb + wave * 32 + (r & 3) + ((r >> 2) << 3) + (hi << 2);
      if (q < N)
        o_out[(size_t)(b * N + q) * 768 + h * 64 + dt * 32 + l31] = f2bf(oacc[dt][r] * inv);
    }
}

// ---------------- host-side orchestration ----------------
static void run_stream(const float* x, int B, int N,
                       const float* ln1_w, const float* ln1_b, const float* proj_b,
                       const float* ln2_w, const float* ln2_b,
                       const float* fc1_b, const float* fc2_b,
                       const ushort* wq, const ushort* wp, const ushort* w1, const ushort* w2,
                       ushort* bufA, ushort* bufQKV, ushort* bufFF,
                       float* out, hipStream_t stream) {
  int M = B * N;
  int gm = (M + 127) / 128;
  int Npad = ((N + 63) / 64) * 64;
  ushort* vtb = bufFF;  // alias: vt used only before fc1 writes bufFF
  ln_kernel<<<M, 64, 0, stream>>>(x, ln1_w, ln1_b, bufA);
  gemm_tile<0><<<dim3(gm, 2304 / 128), 256, 0, stream>>>(bufA, wq, nullptr, nullptr, bufQKV, M, 2304, 768);
  vt_kernel<<<dim3(Npad / 64, B * 12), 256, 0, stream>>>(bufQKV, vtb, N, Npad);
  attn_kernel<<<dim3((N + 127) / 128, B * 12), 256, 0, stream>>>(bufQKV, vtb, bufA, N, Npad);
  gemm_tile<1><<<dim3(gm, 768 / 128), 256, 0, stream>>>(bufA, wp, proj_b, x, out, M, 768, 768);
  ln_kernel<<<M, 64, 0, stream>>>(out, ln2_w, ln2_b, bufA);
  gemm_tile<2><<<dim3(gm, 3072 / 128), 256, 0, stream>>>(bufA, w1, fc1_b, nullptr, bufFF, M, 3072, 768);
  gemm_tile<1><<<dim3(gm, 768 / 128), 256, 0, stream>>>(bufFF, w2, fc2_b, out, out, M, 768, 3072);
}

extern "C" void kernel_launch(void* const* d_in, const int* in_sizes, int n_in,
                              void* d_out, int out_size, void* d_ws, size_t ws_size,
                              hipStream_t stream) {
  const float* x1 = (const float*)d_in[0];
  const float* x2 = (const float*)d_in[1];
  const float* ln1_w = (const float*)d_in[2];
  const float* ln1_b = (const float*)d_in[3];
  const float* qkv_w = (const float*)d_in[4];
  const float* proj_w = (const float*)d_in[5];
  const float* proj_b = (const float*)d_in[6];
  const float* ln2_w = (const float*)d_in[7];
  const float* ln2_b = (const float*)d_in[8];
  const float* fc1_w = (const float*)d_in[9];
  const float* fc1_b = (const float*)d_in[10];
  const float* fc2_w = (const float*)d_in[11];
  const float* fc2_b = (const float*)d_in[12];
  float* out = (float*)d_out;

  const int MPAD = 11008;
  char* ws = (char*)d_ws;
  ushort* wq = (ushort*)ws;            ws += (size_t)2304 * 768 * 2;
  ushort* wp = (ushort*)ws;            ws += (size_t)768 * 768 * 2;
  ushort* w1 = (ushort*)ws;            ws += (size_t)3072 * 768 * 2;
  ushort* w2 = (ushort*)ws;            ws += (size_t)768 * 3072 * 2;
  ushort* bufA = (ushort*)ws;          ws += (size_t)MPAD * 768 * 2;
  ushort* bufQKV = (ushort*)ws;        ws += (size_t)MPAD * 2304 * 2;
  ushort* bufFF = (ushort*)ws;         ws += (size_t)MPAD * 3072 * 2;

  cvt_kernel<<<2048, 256, 0, stream>>>(qkv_w, wq, 2304 * 768);
  cvt_kernel<<<2048, 256, 0, stream>>>(proj_w, wp, 768 * 768);
  cvt_kernel<<<2048, 256, 0, stream>>>(fc1_w, w1, 3072 * 768);
  cvt_kernel<<<2048, 256, 0, stream>>>(fc2_w, w2, 768 * 3072);

  run_stream(x1, 8, 1370, ln1_w, ln1_b, proj_b, ln2_w, ln2_b, fc1_b, fc2_b,
             wq, wp, w1, w2, bufA, bufQKV, bufFF, out, stream);
  run_stream(x2, 8, 257, ln1_w, ln1_b, proj_b, ln2_w, ln2_b, fc1_b, fc2_b,
             wq, wp, w1, w2, bufA, bufQKV, bufFF, out + (size_t)8 * 1370 * 768, stream);
}

// Round 4
// 622.443 us; speedup vs baseline: 2.3571x; 1.0554x over previous
//
#include <hip/hip_runtime.h>
#include <hip/hip_bf16.h>

typedef __attribute__((ext_vector_type(8))) short bf16x8;
typedef __attribute__((ext_vector_type(4))) float f32x4;
typedef __attribute__((ext_vector_type(16))) float f32x16;

#define GL_LDS16(g, l)                                                        \
  __builtin_amdgcn_global_load_lds((const __attribute__((address_space(1))) void*)(g), \
                                   (__attribute__((address_space(3))) void*)(l), 16, 0, 0)

__device__ __forceinline__ ushort f2bf(float f) {
  union { float f; unsigned u; } x; x.f = f;
  unsigned r = x.u + 0x7fffu + ((x.u >> 16) & 1u);
  return (ushort)(r >> 16);
}

// ---------------- f32 -> bf16 convert (grid-stride) ----------------
__global__ void cvt_kernel(const float* __restrict__ in, ushort* __restrict__ out, int n) {
  int i = blockIdx.x * blockDim.x + threadIdx.x;
  int stride = gridDim.x * blockDim.x;
  for (; i < n; i += stride) out[i] = f2bf(in[i]);
}

// ---------------- LayerNorm: 1 wave per row of 768, bf16 out ----------------
__global__ __launch_bounds__(64) void ln_kernel(
    const float* __restrict__ x, const float* __restrict__ w,
    const float* __restrict__ b, ushort* __restrict__ out) {
  int row = blockIdx.x;
  int lane = threadIdx.x;
  const float* xr = x + (size_t)row * 768;
  float4 v[3];
  float s = 0.f, sq = 0.f;
#pragma unroll
  for (int i = 0; i < 3; i++) {
    v[i] = *(const float4*)(xr + i * 256 + lane * 4);
    s += v[i].x + v[i].y + v[i].z + v[i].w;
    sq += v[i].x * v[i].x + v[i].y * v[i].y + v[i].z * v[i].z + v[i].w * v[i].w;
  }
#pragma unroll
  for (int m = 1; m < 64; m <<= 1) { s += __shfl_xor(s, m); sq += __shfl_xor(sq, m); }
  float mean = s * (1.f / 768.f);
  float var = sq * (1.f / 768.f) - mean * mean;
  float rstd = rsqrtf(var + 1e-5f);
  ushort* orow = out + (size_t)row * 768;
#pragma unroll
  for (int i = 0; i < 3; i++) {
    int d = i * 256 + lane * 4;
    float4 wv = *(const float4*)(w + d);
    float4 bv = *(const float4*)(b + d);
    ushort4 o;
    o.x = f2bf((v[i].x - mean) * rstd * wv.x + bv.x);
    o.y = f2bf((v[i].y - mean) * rstd * wv.y + bv.y);
    o.z = f2bf((v[i].z - mean) * rstd * wv.z + bv.z);
    o.w = f2bf((v[i].w - mean) * rstd * wv.w + bv.w);
    *(ushort4*)(orow + d) = o;
  }
}

// ---------------- Tiled GEMM: C[M,N] = A[M,K] * W[N,K]^T ----------------
// MODE 0: store bf16, no bias; q-columns (col<768) pre-scaled by 0.125*log2e
// MODE 1: store f32, +bias +res
// MODE 2: store bf16, +bias, exact GELU
template <int MODE>
__global__ __launch_bounds__(256) void gemm_tile(
    const ushort* __restrict__ A, const ushort* __restrict__ W,
    const float* __restrict__ bias, const float* __restrict__ res,
    void* __restrict__ outp, int M, int N, int K) {
  __shared__ ushort lA[128 * 64];
  __shared__ ushort lB[128 * 64];
  const int t = threadIdx.x;
  const int lane = t & 63, wave = t >> 6;
  const int l15 = lane & 15, lg = lane >> 4;
  const int waveM = wave >> 1, waveN = wave & 1;
  const int rowBlk = blockIdx.x * 128;
  const int colBlk = blockIdx.y * 128;

  const int srow = (wave << 3) + (lane >> 3);
  const int schunk = lane & 7;

  f32x4 acc[4][4] = {};

  for (int k0 = 0; k0 < K; k0 += 64) {
    if (k0) __syncthreads();
#pragma unroll
    for (int i = 0; i < 4; i++) {
      int row = i * 32 + srow;
      int gchunk = schunk ^ (row & 7);
      GL_LDS16(A + (size_t)(rowBlk + row) * K + k0 + gchunk * 8,
               &lA[row * 64 + schunk * 8]);
      GL_LDS16(W + (size_t)(colBlk + row) * K + k0 + gchunk * 8,
               &lB[row * 64 + schunk * 8]);
    }
    __syncthreads();
#pragma unroll
    for (int kk = 0; kk < 2; kk++) {
      bf16x8 af[4], bfr[4];
#pragma unroll
      for (int m = 0; m < 4; m++) {
        int row = waveM * 64 + m * 16 + l15;
        af[m] = *(const bf16x8*)&lA[row * 64 + ((kk * 32 + lg * 8) ^ ((row & 7) << 3))];
      }
#pragma unroll
      for (int c = 0; c < 4; c++) {
        int row = waveN * 64 + c * 16 + l15;
        bfr[c] = *(const bf16x8*)&lB[row * 64 + ((kk * 32 + lg * 8) ^ ((row & 7) << 3))];
      }
#pragma unroll
      for (int m = 0; m < 4; m++)
#pragma unroll
        for (int c = 0; c < 4; c++)
          acc[m][c] = __builtin_amdgcn_mfma_f32_16x16x32_bf16(af[m], bfr[c], acc[m][c], 0, 0, 0);
    }
  }

  const float qsc = (MODE == 0 && colBlk < 768) ? 0.18033688011112042f : 1.f;
#pragma unroll
  for (int m = 0; m < 4; m++) {
    int rowB = rowBlk + waveM * 64 + m * 16 + lg * 4;
#pragma unroll
    for (int c = 0; c < 4; c++) {
      int col = colBlk + waveN * 64 + c * 16 + l15;
      float bv = (MODE != 0) ? bias[col] : 0.f;
#pragma unroll
      for (int j = 0; j < 4; j++) {
        int r = rowB + j;
        if (r < M) {
          float v = acc[m][c][j] + bv;
          size_t idx = (size_t)r * N + col;
          if (MODE == 1) {
            ((float*)outp)[idx] = v + res[idx];
          } else if (MODE == 2) {
            float g = 0.5f * v * (1.f + erff(v * 0.70710678118f));
            ((ushort*)outp)[idx] = f2bf(g);
          } else {
            ((ushort*)outp)[idx] = f2bf(v * qsc);
          }
        }
      }
    }
  }
}

// ---------------- prep: per-(bh, kv64) K and V tiles in attn-LDS layout ----------------
// ktile slot s = dchunk*64 + krow  (16B = K[k0+krow][dchunk*8 + j])
// vtile slot s = kchunk*64 + d     (16B = V[k0+kchunk*8+j][d])
__global__ __launch_bounds__(256) void prep_kernel(
    const ushort* __restrict__ qkv, ushort* __restrict__ kt2,
    ushort* __restrict__ vt2, int N, int nkv) {
  __shared__ ushort lT[64 * 68];
  const int t = threadIdx.x;
  const int kv = blockIdx.x;
  const int bh = blockIdx.y;
  const int b = bh / 12, h = bh % 12;
  const int k0 = kv * 64;
  const ushort* Kp = qkv + (size_t)b * N * 2304 + 768 + h * 64;
  const ushort* Vp = Kp + 768;
  ushort* ktile = kt2 + ((size_t)bh * nkv + kv) * 4096;
  ushort* vtile = vt2 + ((size_t)bh * nkv + kv) * 4096;
#pragma unroll
  for (int p = 0; p < 2; p++) {
    int s = p * 256 + t;
    int chunk = s >> 6, krow = s & 63;
    ushort4 v0 = {0, 0, 0, 0}, v1 = {0, 0, 0, 0};
    if (k0 + krow < N) {
      const ushort* src = Kp + (size_t)(k0 + krow) * 2304 + chunk * 8;
      v0 = *(const ushort4*)src;
      v1 = *(const ushort4*)(src + 4);
    }
    *(ushort4*)&ktile[s * 8] = v0;
    *(ushort4*)&ktile[s * 8 + 4] = v1;
  }
#pragma unroll
  for (int p = 0; p < 2; p++) {
    int nl = p * 32 + (t >> 3);
    int dc = t & 7;
    ushort4 v0 = {0, 0, 0, 0}, v1 = {0, 0, 0, 0};
    if (k0 + nl < N) {
      const ushort* src = Vp + (size_t)(k0 + nl) * 2304 + dc * 8;
      v0 = *(const ushort4*)src;
      v1 = *(const ushort4*)(src + 4);
    }
    *(ushort4*)&lT[nl * 68 + dc * 8] = v0;
    *(ushort4*)&lT[nl * 68 + dc * 8 + 4] = v1;
  }
  __syncthreads();
#pragma unroll
  for (int p = 0; p < 2; p++) {
    int s = p * 256 + t;
    int kchunk = s >> 6, d = s & 63;
    ushort o[8];
#pragma unroll
    for (int j = 0; j < 8; j++) o[j] = lT[(kchunk * 8 + j) * 68 + d];
    *(ushort4*)&vtile[s * 8] = *(ushort4*)o;
    *(ushort4*)&vtile[s * 8 + 4] = *(ushort4*)(o + 4);
  }
}

// ---------------- Flash attention: 4 waves/block, 32 q-rows/wave ----------------
// Q pre-scaled by 0.125*log2e; swapped QK^T 32x32x16; permlane32_swap for
// cross-half reduce + P redistribution; T13 defer-max (THR=8 log2 units).
__global__ __launch_bounds__(256) void attn_kernel(
    const ushort* __restrict__ qkv, const ushort* __restrict__ kt2,
    const ushort* __restrict__ vt2, ushort* __restrict__ o_out, int N, int nkv) {
  __shared__ ushort lK[4096];
  __shared__ ushort lV[4096];
  const int t = threadIdx.x;
  const int lane = t & 63, wave = t >> 6;
  const int l31 = lane & 31, hi = lane >> 5;
  const int qb = blockIdx.x * 128;
  const int bh = blockIdx.y;
  const int b = bh / 12, h = bh % 12;
  const ushort* Qp = qkv + (size_t)b * N * 2304 + h * 64;
  const int qrow = qb + wave * 32 + l31;
  bf16x8 qf[4];
#pragma unroll
  for (int kc = 0; kc < 4; kc++)
    qf[kc] = *(const bf16x8*)(Qp + (size_t)qrow * 2304 + kc * 16 + hi * 8);

  f32x16 oacc[2] = {};
  float mrun = -1e30f, lrun = 0.f;

  for (int kv = 0; kv < nkv; kv++) {
    if (kv) __syncthreads();
    const ushort* Ktile = kt2 + ((size_t)bh * nkv + kv) * 4096;
    const ushort* Vtile = vt2 + ((size_t)bh * nkv + kv) * 4096;
#pragma unroll
    for (int p = 0; p < 2; p++) {
      int s = p * 256 + t;
      GL_LDS16(Ktile + s * 8, &lK[s * 8]);
      GL_LDS16(Vtile + s * 8, &lV[s * 8]);
    }
    __syncthreads();
    const bool fullTile = (kv * 64 + 64 <= N);
#pragma unroll
    for (int kt = 0; kt < 2; kt++) {
      f32x16 sacc = {};
#pragma unroll
      for (int kc = 0; kc < 4; kc++) {
        bf16x8 kf = *(const bf16x8*)&lK[(((kc * 2 + hi) << 6) + kt * 32 + l31) * 8];
        sacc = __builtin_amdgcn_mfma_f32_32x32x16_bf16(kf, qf[kc], sacc, 0, 0, 0);
      }
      float z[16];
      float mx = -1e30f;
#pragma unroll
      for (int r = 0; r < 16; r++) {
        z[r] = sacc[r];
        if (!fullTile) {
          int kg = kv * 64 + kt * 32 + (r & 3) + ((r >> 2) << 3) + (hi << 2);
          if (kg >= N) z[r] = -1e30f;
        }
        mx = fmaxf(mx, z[r]);
      }
      {
        float a = mx, bx = mx;
        asm("v_permlane32_swap_b32 %0, %1" : "+&v"(a), "+v"(bx));
        mx = fmaxf(a, bx);
      }
      if (!__all(mx <= mrun + 8.f)) {
        float mnew = fmaxf(mrun, mx);
        float corr = exp2f(mrun - mnew);
        lrun *= corr;
        oacc[0] *= corr;
        oacc[1] *= corr;
        mrun = mnew;
      }
      float rs = 0.f;
#pragma unroll
      for (int r = 0; r < 16; r++) { z[r] = exp2f(z[r] - mrun); rs += z[r]; }
      {
        float a = rs, bx = rs;
        asm("v_permlane32_swap_b32 %0, %1" : "+&v"(a), "+v"(bx));
        rs = a + bx;
      }
      lrun += rs;
      unsigned w0[4], w1[4];
#pragma unroll
      for (int rr = 0; rr < 4; rr++) {
        asm("v_cvt_pk_bf16_f32 %0, %1, %2" : "=v"(w0[rr]) : "v"(z[4 * rr]), "v"(z[4 * rr + 1]));
        asm("v_cvt_pk_bf16_f32 %0, %1, %2" : "=v"(w1[rr]) : "v"(z[4 * rr + 2]), "v"(z[4 * rr + 3]));
      }
#pragma unroll
      for (int kc2 = 0; kc2 < 2; kc2++) {
        unsigned ua = w0[2 * kc2], ub = w0[2 * kc2 + 1];
        unsigned uc = w1[2 * kc2], ud = w1[2 * kc2 + 1];
        asm("v_permlane32_swap_b32 %0, %1" : "+&v"(ua), "+v"(ub));
        asm("v_permlane32_swap_b32 %0, %1" : "+&v"(uc), "+v"(ud));
        union { unsigned u[4]; bf16x8 v; } pa;
        pa.u[0] = ua;  // k = 8hi + {0,1}
        pa.u[1] = uc;  // k = 8hi + {2,3}
        pa.u[2] = ub;  // k = 8hi + {4,5}
        pa.u[3] = ud;  // k = 8hi + {6,7}
        int kcg = kt * 2 + kc2;
#pragma unroll
        for (int dt = 0; dt < 2; dt++) {
          bf16x8 vf = *(const bf16x8*)&lV[(((kcg * 2 + hi) << 6) + dt * 32 + l31) * 8];
          oacc[dt] = __builtin_amdgcn_mfma_f32_32x32x16_bf16(pa.v, vf, oacc[dt], 0, 0, 0);
        }
      }
    }
  }
  float inv = 1.f / lrun;
#pragma unroll
  for (int dt = 0; dt < 2; dt++)
#pragma unroll
    for (int r = 0; r < 16; r++) {
      int q = qb + wave * 32 + (r & 3) + ((r >> 2) << 3) + (hi << 2);
      if (q < N)
        o_out[(size_t)(b * N + q) * 768 + h * 64 + dt * 32 + l31] = f2bf(oacc[dt][r] * inv);
    }
}

// ---------------- host-side orchestration ----------------
static void run_stream(const float* x, int B, int N,
                       const float* ln1_w, const float* ln1_b, const float* proj_b,
                       const float* ln2_w, const float* ln2_b,
                       const float* fc1_b, const float* fc2_b,
                       const ushort* wq, const ushort* wp, const ushort* w1, const ushort* w2,
                       ushort* bufA, ushort* bufQKV, ushort* bufFF,
                       float* out, hipStream_t stream) {
  int M = B * N;
  int gm = (M + 127) / 128;
  int nkv = (N + 63) / 64;
  int BH = B * 12;
  ushort* kt2 = bufFF;  // alias: used only before fc1 writes bufFF
  ushort* vt2 = bufFF + (size_t)BH * nkv * 4096;
  ln_kernel<<<M, 64, 0, stream>>>(x, ln1_w, ln1_b, bufA);
  gemm_tile<0><<<dim3(gm, 2304 / 128), 256, 0, stream>>>(bufA, wq, nullptr, nullptr, bufQKV, M, 2304, 768);
  prep_kernel<<<dim3(nkv, BH), 256, 0, stream>>>(bufQKV, kt2, vt2, N, nkv);
  attn_kernel<<<dim3((N + 127) / 128, BH), 256, 0, stream>>>(bufQKV, kt2, vt2, bufA, N, nkv);
  gemm_tile<1><<<dim3(gm, 768 / 128), 256, 0, stream>>>(bufA, wp, proj_b, x, out, M, 768, 768);
  ln_kernel<<<M, 64, 0, stream>>>(out, ln2_w, ln2_b, bufA);
  gemm_tile<2><<<dim3(gm, 3072 / 128), 256, 0, stream>>>(bufA, w1, fc1_b, nullptr, bufFF, M, 3072, 768);
  gemm_tile<1><<<dim3(gm, 768 / 128), 256, 0, stream>>>(bufFF, w2, fc2_b, out, out, M, 768, 3072);
}

extern "C" void kernel_launch(void* const* d_in, const int* in_sizes, int n_in,
                              void* d_out, int out_size, void* d_ws, size_t ws_size,
                              hipStream_t stream) {
  const float* x1 = (const float*)d_in[0];
  const float* x2 = (const float*)d_in[1];
  const float* ln1_w = (const float*)d_in[2];
  const float* ln1_b = (const float*)d_in[3];
  const float* qkv_w = (const float*)d_in[4];
  const float* proj_w = (const float*)d_in[5];
  const float* proj_b = (const float*)d_in[6];
  const float* ln2_w = (const float*)d_in[7];
  const float* ln2_b = (const float*)d_in[8];
  const float* fc1_w = (const float*)d_in[9];
  const float* fc1_b = (const float*)d_in[10];
  const float* fc2_w = (const float*)d_in[11];
  const float* fc2_b = (const float*)d_in[12];
  float* out = (float*)d_out;

  const int MPAD = 11008;
  char* ws = (char*)d_ws;
  ushort* wq = (ushort*)ws;            ws += (size_t)2304 * 768 * 2;
  ushort* wp = (ushort*)ws;            ws += (size_t)768 * 768 * 2;
  ushort* w1 = (ushort*)ws;            ws += (size_t)3072 * 768 * 2;
  ushort* w2 = (ushort*)ws;            ws += (size_t)768 * 3072 * 2;
  ushort* bufA = (ushort*)ws;          ws += (size_t)MPAD * 768 * 2;
  ushort* bufQKV = (ushort*)ws;        ws += (size_t)MPAD * 2304 * 2;
  ushort* bufFF = (ushort*)ws;         ws += (size_t)MPAD * 3072 * 2;

  cvt_kernel<<<2048, 256, 0, stream>>>(qkv_w, wq, 2304 * 768);
  cvt_kernel<<<2048, 256, 0, stream>>>(proj_w, wp, 768 * 768);
  cvt_kernel<<<2048, 256, 0, stream>>>(fc1_w, w1, 3072 * 768);
  cvt_kernel<<<2048, 256, 0, stream>>>(fc2_w, w2, 768 * 3072);

  run_stream(x1, 8, 1370, ln1_w, ln1_b, proj_b, ln2_w, ln2_b, fc1_b, fc2_b,
             wq, wp, w1, w2, bufA, bufQKV, bufFF, out, stream);
  run_stream(x2, 8, 257, ln1_w, ln1_b, proj_b, ln2_w, ln2_b, fc1_b, fc2_b,
             wq, wp, w1, w2, bufA, bufQKV, bufFF, out + (size_t)8 * 1370 * 768, stream);
}